// Round 14
// baseline (92.173 us; speedup 1.0000x reference)
//
#include <hip/hip_runtime.h>
#include <math.h>

#define HH 1024
#define WW 1024
#define PADK 15
#define RB 16
#define TPB 512
#define EPSV 1e-5f
#define INV_K2 (1.0f / 961.0f)

typedef float v4f __attribute__((ext_vector_type(4)));

__device__ __forceinline__ v4f ld4v(const float* p) {
    return *reinterpret_cast<const v4f*>(p);
}

// XOR bank swizzle on LDS word index: b2 ^= b5 (r8-verified: conflicts 47M->6.8M).
__device__ __forceinline__ int swz4(int w) {
    return w ^ (((w >> 5) & 1) << 2);
}

// Horizontal 31-window sums for the 8 consecutive cols owned by a lane
// (r7-r13-verified arithmetic).
__device__ __forceinline__ void hwin31(const float* __restrict__ sw, int bw,
                                       float wins[8]) {
    v4f R0 = ld4v(sw + swz4(bw));          // wv[0..3]
    v4f R1 = ld4v(sw + swz4(bw + 4));      // wv[4..7]
    v4f acc = R1;
    acc += ld4v(sw + swz4(bw + 8));
    acc += ld4v(sw + swz4(bw + 12));
    acc += ld4v(sw + swz4(bw + 16));
    acc += ld4v(sw + swz4(bw + 20));
    acc += ld4v(sw + swz4(bw + 24));
    acc += ld4v(sw + swz4(bw + 28));       // ..wv[31]
    v4f R8 = ld4v(sw + swz4(bw + 32));     // wv[32..35]
    v4f R9 = ld4v(sw + swz4(bw + 36));     // wv[36..39]

    float base = (acc.x + acc.y) + (acc.z + acc.w);   // wv[4..31]

    wins[0] = base + ((R0.y + R0.z) + R0.w);          // + wv[1..3]
    wins[1] = wins[0] + (R8.x - R0.y);
    wins[2] = wins[1] + (R8.y - R0.z);
    wins[3] = wins[2] + (R8.z - R0.w);
    wins[4] = wins[3] + (R8.w - R1.x);
    wins[5] = wins[4] + (R9.x - R1.y);
    wins[6] = wins[5] + (R9.y - R1.z);
    wins[7] = wins[6] + (R9.z - R1.w);
}

// Sliding-window vertical-sum update (r12's exact op order).
__device__ __forceinline__ void update_sums(const float* __restrict__ img,
                                            int radd, int rsub, int c0,
                                            int hcol, bool hvalid,
                                            v4f& sa, v4f& sb, v4f& qa, v4f& qb,
                                            v4f& hs, v4f& hs2) {
    if (radd < HH) {
        const float* rowp = img + (size_t)radd * WW;
        v4f va = ld4v(rowp + c0);
        v4f vb = ld4v(rowp + c0 + 4);
        sa += va;      sb += vb;
        qa += va * va; qb += vb * vb;
        if (hvalid) {
            v4f hv = ld4v(rowp + hcol);
            hs  += hv;
            hs2 += hv * hv;
        }
    }
    if (rsub >= 0) {
        const float* rowp = img + (size_t)rsub * WW;
        v4f va = ld4v(rowp + c0);
        v4f vb = ld4v(rowp + c0 + 4);
        sa -= va;      sb -= vb;
        qa -= va * va; qb -= vb * vb;
        if (hvalid) {
            v4f hv = ld4v(rowp + hcol);
            hs  -= hv;
            hs2 -= hv * hv;
        }
    }
}

// Pointwise LCN tail for 8 cols (r12-verified). Loads its own center pixels
// (L2-hot: this wave read that row as an entering row 15 iterations ago) to
// keep register lifetimes short -- r13's 80-VGPR lesson.
__device__ __forceinline__ void pointwise8(const float winx[8], const float winq[8],
                                           const float* __restrict__ crow,
                                           float* dst) {
    const v4f xc0 = ld4v(crow);
    const v4f xc1 = ld4v(crow + 4);
    v4f wxv0 = {winx[0], winx[1], winx[2], winx[3]};
    v4f wxv1 = {winx[4], winx[5], winx[6], winx[7]};
    v4f wqv0 = {winq[0], winq[1], winq[2], winq[3]};
    v4f wqv1 = {winq[4], winq[5], winq[6], winq[7]};
    v4f mean0 = wxv0 * INV_K2;
    v4f mean1 = wxv1 * INV_K2;
    v4f sqv0  = wqv0 * INV_K2;
    v4f sqv1  = wqv1 * INV_K2;
    v4f var0  = sqv0 - mean0 * mean0;
    v4f var1  = sqv1 - mean1 * mean1;
    const v4f epsv = {EPSV, EPSV, EPSV, EPSV};
    var0 = __builtin_elementwise_max(var0, epsv);
    var1 = __builtin_elementwise_max(var1, epsv);
    v4f d0 = xc0 - mean0;
    v4f d1 = xc1 - mean1;

    v4f o0, o1;
    #pragma unroll
    for (int q = 0; q < 4; ++q) {
        float rs  = __builtin_amdgcn_rsqf(var0[q]);
        float nrm = d0[q] * rs;
        float e   = __expf(-0.5f * nrm);
        o0[q] = xc0[q] * 0.2f + 0.8f * __builtin_amdgcn_rcpf(1.0f + e);
    }
    #pragma unroll
    for (int q = 0; q < 4; ++q) {
        float rs  = __builtin_amdgcn_rsqf(var1[q]);
        float nrm = d1[q] * rs;
        float e   = __expf(-0.5f * nrm);
        o1[q] = xc1[q] * 0.2f + 0.8f * __builtin_amdgcn_rcpf(1.0f + e);
    }
    *reinterpret_cast<v4f*>(dst)     = o0;
    *reinterpret_cast<v4f*>(dst + 4) = o1;
}

__global__ __launch_bounds__(TPB) void lcn_kernel(const float* __restrict__ x,
                                                  float* __restrict__ out) {
    // r12 geometry (verified best): 8 waves/block = 2 col-halves x 4 row-bands
    // of 16 rows -> 64-row slab. Wave owns a 512-col stripe, 8 cols/lane,
    // swizzled per-wave LDS, no __syncthreads, XCD-chunked block swizzle.
    // 2-row software pipeline (r13) with MINIMAL register lifetimes: center
    // pixels loaded inside pointwise8, only winxA/winqA cross the row phases.
    __shared__ __align__(16) float sxl[8][552];
    __shared__ __align__(16) float sql[8][552];

    const int bid  = blockIdx.x;
    const int xcd  = bid & 7;           // hw XCD (round-robin heuristic)
    const int k    = bid >> 3;          // 0..63
    const int b    = xcd * 4 + (k >> 4);   // image: 4 per XCD
    const int seg  = k & 15;            // 64-row slab within image
    const int t    = threadIdx.x;
    const int w    = t >> 6;            // wave 0..7
    const int l    = t & 63;            // lane
    const int half = w & 1;             // column half
    const int band = w >> 1;            // row band 0..3
    const int r0   = seg * 64 + band * RB;
    const int wc0  = half * 512;
    const int c0   = wc0 + l * 8;       // lane owns cols c0..c0+7
    const int bw   = 8 * l;             // window read base (logical word)

    float* __restrict__ sxw = sxl[w];
    float* __restrict__ sqw = sql[w];

    // halo: lanes 0-3 left halo float4s, lanes 4-7 right halo float4s
    int hcol = 0;
    const bool hlane = (l < 8);
    if (l < 4)      hcol = wc0 - 16 + 4 * l;
    else if (l < 8) hcol = wc0 + 512 + 4 * (l - 4);
    const bool hvalid = hlane && (hcol >= 0) && (hcol < WW);
    const int  hw_    = (l < 4) ? 4 * l : 528 + 4 * (l - 4);  // logical word
    const int  hidx   = swz4(hw_);                            // swizzled

    const int ow0 = swz4(16 + 8 * l);        // owned write base (quad a)
    const int ow1 = swz4(20 + 8 * l);        // owned write base (quad b)

    const float* __restrict__ img  = x   + (size_t)b * HH * WW;
    float* __restrict__       oimg = out + (size_t)b * HH * WW;

    v4f sa  = {0.f, 0.f, 0.f, 0.f};   // vertical sums c0..c0+3
    v4f sb  = {0.f, 0.f, 0.f, 0.f};   // c0+4..c0+7
    v4f qa  = {0.f, 0.f, 0.f, 0.f};   // vertical sq-sums
    v4f qb  = {0.f, 0.f, 0.f, 0.f};
    v4f hs  = {0.f, 0.f, 0.f, 0.f};   // halo sums
    v4f hs2 = {0.f, 0.f, 0.f, 0.f};

    // --- init vertical sliding sums for output row r0 ---
    {
        int lo = r0 - PADK; if (lo < 0) lo = 0;
        int hi = r0 + PADK; if (hi > HH - 1) hi = HH - 1;
        for (int r = lo; r <= hi; ++r) {
            const float* rowp = img + (size_t)r * WW;
            v4f va = ld4v(rowp + c0);
            v4f vb = ld4v(rowp + c0 + 4);
            sa += va;      sb += vb;
            qa += va * va; qb += vb * vb;
            if (hvalid) {
                v4f hv = ld4v(rowp + hcol);
                hs  += hv;
                hs2 += hv * hv;
            }
        }
    }

    for (int i2 = 0; i2 < RB; i2 += 2) {
        const int ri = r0 + i2;

        // bring sums to row ri (no-op on first pair)
        if (i2 > 0) {
            update_sums(img, ri + PADK, ri - PADK - 1, c0, hcol, hvalid,
                        sa, sb, qa, qb, hs, hs2);
        }

        // write row ri sums
        *reinterpret_cast<v4f*>(sxw + ow0) = sa;
        *reinterpret_cast<v4f*>(sxw + ow1) = sb;
        *reinterpret_cast<v4f*>(sqw + ow0) = qa;
        *reinterpret_cast<v4f*>(sqw + ow1) = qb;
        if (hlane) {
            *reinterpret_cast<v4f*>(sxw + hidx) = hs;
            *reinterpret_cast<v4f*>(sqw + hidx) = hs2;
        }

        // advance sums to row ri+1 (issues its update loads now; their
        // latency is covered by row ri's reads below)
        update_sums(img, ri + 1 + PADK, ri - PADK, c0, hcol, hvalid,
                    sa, sb, qa, qb, hs, hs2);

        // read windows for row ri (before row ri+1 is written; DS in-order)
        float winxA[8], winqA[8];
        hwin31(sxw, bw, winxA);
        hwin31(sqw, bw, winqA);

        // write row ri+1 sums (same buffer; queues after the reads above)
        *reinterpret_cast<v4f*>(sxw + ow0) = sa;
        *reinterpret_cast<v4f*>(sxw + ow1) = sb;
        *reinterpret_cast<v4f*>(sqw + ow0) = qa;
        *reinterpret_cast<v4f*>(sqw + ow1) = qb;
        if (hlane) {
            *reinterpret_cast<v4f*>(sxw + hidx) = hs;
            *reinterpret_cast<v4f*>(sqw + hidx) = hs2;
        }

        // pointwise row ri (VALU overlaps row ri+1's LDS round-trip)
        pointwise8(winxA, winqA, img + (size_t)ri * WW + c0,
                   oimg + (size_t)ri * WW + c0);

        // read windows + pointwise for row ri+1
        float winxB[8], winqB[8];
        hwin31(sxw, bw, winxB);
        hwin31(sqw, bw, winqB);
        pointwise8(winxB, winqB, img + (size_t)(ri + 1) * WW + c0,
                   oimg + (size_t)(ri + 1) * WW + c0);
    }
}

extern "C" void kernel_launch(void* const* d_in, const int* in_sizes, int n_in,
                              void* d_out, int out_size, void* d_ws, size_t ws_size,
                              hipStream_t stream) {
    const float* xin = (const float*)d_in[0];
    float* out = (float*)d_out;
    const int B = in_sizes[0] / (HH * WW);   // 32
    dim3 grid(B * 16);                       // 512 blocks x 8 waves
    dim3 block(TPB);
    hipLaunchKernelGGL(lcn_kernel, grid, block, 0, stream, xin, out);
}

// Round 15
// 87.510 us; speedup vs baseline: 1.0533x; 1.0533x over previous
//
#include <hip/hip_runtime.h>
#include <math.h>

#define HH 1024
#define WW 1024
#define PADK 15
#define RB 16
#define TPB 512
#define EPSV 1e-5f
#define INV_K2 (1.0f / 961.0f)

typedef float v4f __attribute__((ext_vector_type(4)));

__device__ __forceinline__ v4f ld4v(const float* p) {
    return *reinterpret_cast<const v4f*>(p);
}

// XOR bank swizzle on LDS word index: b2 ^= b5 (r8-verified: conflicts 47M->6.8M).
__device__ __forceinline__ int swz4(int w) {
    return w ^ (((w >> 5) & 1) << 2);
}

// Horizontal 31-window sums for the 8 consecutive cols owned by a lane
// (r7-r12-verified arithmetic; base accumulation vectorized for packed fp32).
__device__ __forceinline__ void hwin31(const float* __restrict__ sw, int bw,
                                       float wins[8]) {
    v4f R0 = ld4v(sw + swz4(bw));          // wv[0..3]
    v4f R1 = ld4v(sw + swz4(bw + 4));      // wv[4..7]
    v4f acc = R1;
    acc += ld4v(sw + swz4(bw + 8));
    acc += ld4v(sw + swz4(bw + 12));
    acc += ld4v(sw + swz4(bw + 16));
    acc += ld4v(sw + swz4(bw + 20));
    acc += ld4v(sw + swz4(bw + 24));
    acc += ld4v(sw + swz4(bw + 28));       // ..wv[31]
    v4f R8 = ld4v(sw + swz4(bw + 32));     // wv[32..35]
    v4f R9 = ld4v(sw + swz4(bw + 36));     // wv[36..39]

    float base = (acc.x + acc.y) + (acc.z + acc.w);   // wv[4..31]

    wins[0] = base + ((R0.y + R0.z) + R0.w);          // + wv[1..3]
    wins[1] = wins[0] + (R8.x - R0.y);
    wins[2] = wins[1] + (R8.y - R0.z);
    wins[3] = wins[2] + (R8.z - R0.w);
    wins[4] = wins[3] + (R8.w - R1.x);
    wins[5] = wins[4] + (R9.x - R1.y);
    wins[6] = wins[5] + (R9.y - R1.z);
    wins[7] = wins[6] + (R9.z - R1.w);
}

__global__ __launch_bounds__(TPB) void lcn_kernel(const float* __restrict__ x,
                                                  float* __restrict__ out) {
    // r12 configuration (session-best, verified): 8 waves/block = 2 col-halves
    // x 4 row-bands of 16 rows -> 64-row slab (block amp 1.47x). Wave owns a
    // 512-col stripe, 8 cols/lane, swizzled per-wave LDS, no __syncthreads.
    // XCD-chunked block swizzle: XCD x owns images 4x..4x+3.
    // Packed-fp32 (ext-vector) arithmetic + rsq(var) shortcut.
    // NOTE: 2-row software pipelining falsified twice (r13: VGPR 80, r14:
    // VGPR 72 -- both cross the 64-VGPR occupancy step, occ 40%->22%).
    __shared__ __align__(16) float sxl[8][552];
    __shared__ __align__(16) float sql[8][552];

    const int bid  = blockIdx.x;
    const int xcd  = bid & 7;           // hw XCD (round-robin heuristic)
    const int k    = bid >> 3;          // 0..63
    const int b    = xcd * 4 + (k >> 4);   // image: 4 per XCD
    const int seg  = k & 15;            // 64-row slab within image
    const int t    = threadIdx.x;
    const int w    = t >> 6;            // wave 0..7
    const int l    = t & 63;            // lane
    const int half = w & 1;             // column half
    const int band = w >> 1;            // row band 0..3
    const int r0   = seg * 64 + band * RB;
    const int wc0  = half * 512;
    const int c0   = wc0 + l * 8;       // lane owns cols c0..c0+7
    const int bw   = 8 * l;             // window read base (logical word)

    float* __restrict__ sxw = sxl[w];
    float* __restrict__ sqw = sql[w];

    // halo: lanes 0-3 left halo float4s, lanes 4-7 right halo float4s
    int hcol = 0;
    const bool hlane = (l < 8);
    if (l < 4)      hcol = wc0 - 16 + 4 * l;
    else if (l < 8) hcol = wc0 + 512 + 4 * (l - 4);
    const bool hvalid = hlane && (hcol >= 0) && (hcol < WW);
    const int  hw_    = (l < 4) ? 4 * l : 528 + 4 * (l - 4);  // logical word
    const int  hidx   = swz4(hw_);                            // swizzled

    const int ow0 = swz4(16 + 8 * l);        // owned write base (quad a)
    const int ow1 = swz4(20 + 8 * l);        // owned write base (quad b)

    const float* __restrict__ img  = x   + (size_t)b * HH * WW;
    float* __restrict__       oimg = out + (size_t)b * HH * WW;

    v4f sa  = {0.f, 0.f, 0.f, 0.f};   // vertical sums c0..c0+3
    v4f sb  = {0.f, 0.f, 0.f, 0.f};   // c0+4..c0+7
    v4f qa  = {0.f, 0.f, 0.f, 0.f};   // vertical sq-sums
    v4f qb  = {0.f, 0.f, 0.f, 0.f};
    v4f hs  = {0.f, 0.f, 0.f, 0.f};   // halo sums
    v4f hs2 = {0.f, 0.f, 0.f, 0.f};

    // --- init vertical sliding sums for output row r0 ---
    {
        int lo = r0 - PADK; if (lo < 0) lo = 0;
        int hi = r0 + PADK; if (hi > HH - 1) hi = HH - 1;
        for (int r = lo; r <= hi; ++r) {
            const float* rowp = img + (size_t)r * WW;
            v4f va = ld4v(rowp + c0);
            v4f vb = ld4v(rowp + c0 + 4);
            sa += va;      sb += vb;
            qa += va * va; qb += vb * vb;
            if (hvalid) {
                v4f hv = ld4v(rowp + hcol);
                hs  += hv;
                hs2 += hv * hv;
            }
        }
    }

    for (int i = 0; i < RB; ++i) {
        const int orow = r0 + i;
        if (i > 0) {
            const int radd = orow + PADK;
            const int rsub = orow - PADK - 1;
            if (radd < HH) {
                const float* rowp = img + (size_t)radd * WW;
                v4f va = ld4v(rowp + c0);
                v4f vb = ld4v(rowp + c0 + 4);
                sa += va;      sb += vb;
                qa += va * va; qb += vb * vb;
                if (hvalid) {
                    v4f hv = ld4v(rowp + hcol);
                    hs  += hv;
                    hs2 += hv * hv;
                }
            }
            if (rsub >= 0) {
                const float* rowp = img + (size_t)rsub * WW;
                v4f va = ld4v(rowp + c0);
                v4f vb = ld4v(rowp + c0 + 4);
                sa -= va;      sb -= vb;
                qa -= va * va; qb -= vb * vb;
                if (hvalid) {
                    v4f hv = ld4v(rowp + hcol);
                    hs  -= hv;
                    hs2 -= hv * hv;
                }
            }
        }

        // write this wave's vertical sums (owned + halo), swizzled
        *reinterpret_cast<v4f*>(sxw + ow0) = sa;
        *reinterpret_cast<v4f*>(sxw + ow1) = sb;
        *reinterpret_cast<v4f*>(sqw + ow0) = qa;
        *reinterpret_cast<v4f*>(sqw + ow1) = qb;
        if (hlane) {
            *reinterpret_cast<v4f*>(sxw + hidx) = hs;    // zeros when !hvalid
            *reinterpret_cast<v4f*>(sqw + hidx) = hs2;
        }
        // no barrier: DS ops are in-order within a wave

        // center-row load issued before the LDS round-trip (latency cover)
        const float* crow = img + (size_t)orow * WW + c0;
        const v4f xc0 = ld4v(crow);
        const v4f xc1 = ld4v(crow + 4);

        // --- horizontal 31-window sums for the 8 owned cols ---
        float winx[8], winq[8];
        hwin31(sxw, bw, winx);
        hwin31(sqw, bw, winq);

        // --- pointwise: packed algebra + scalar transcendental tail ---
        v4f wxv0 = {winx[0], winx[1], winx[2], winx[3]};
        v4f wxv1 = {winx[4], winx[5], winx[6], winx[7]};
        v4f wqv0 = {winq[0], winq[1], winq[2], winq[3]};
        v4f wqv1 = {winq[4], winq[5], winq[6], winq[7]};
        v4f mean0 = wxv0 * INV_K2;
        v4f mean1 = wxv1 * INV_K2;
        v4f sqv0  = wqv0 * INV_K2;
        v4f sqv1  = wqv1 * INV_K2;
        v4f var0  = sqv0 - mean0 * mean0;
        v4f var1  = sqv1 - mean1 * mean1;
        const v4f epsv = {EPSV, EPSV, EPSV, EPSV};
        var0 = __builtin_elementwise_max(var0, epsv);
        var1 = __builtin_elementwise_max(var1, epsv);
        v4f d0 = xc0 - mean0;
        v4f d1 = xc1 - mean1;

        v4f o0, o1;
        #pragma unroll
        for (int q = 0; q < 4; ++q) {
            float rs  = __builtin_amdgcn_rsqf(var0[q]);
            float nrm = d0[q] * rs;
            float e   = __expf(-0.5f * nrm);
            o0[q] = xc0[q] * 0.2f + 0.8f * __builtin_amdgcn_rcpf(1.0f + e);
        }
        #pragma unroll
        for (int q = 0; q < 4; ++q) {
            float rs  = __builtin_amdgcn_rsqf(var1[q]);
            float nrm = d1[q] * rs;
            float e   = __expf(-0.5f * nrm);
            o1[q] = xc1[q] * 0.2f + 0.8f * __builtin_amdgcn_rcpf(1.0f + e);
        }
        float* orow_p = oimg + (size_t)orow * WW + c0;
        *reinterpret_cast<v4f*>(orow_p)     = o0;
        *reinterpret_cast<v4f*>(orow_p + 4) = o1;
    }
}

extern "C" void kernel_launch(void* const* d_in, const int* in_sizes, int n_in,
                              void* d_out, int out_size, void* d_ws, size_t ws_size,
                              hipStream_t stream) {
    const float* xin = (const float*)d_in[0];
    float* out = (float*)d_out;
    const int B = in_sizes[0] / (HH * WW);   // 32
    dim3 grid(B * 16);                       // 512 blocks x 8 waves
    dim3 block(TPB);
    hipLaunchKernelGGL(lcn_kernel, grid, block, 0, stream, xin, out);
}